// Round 7
// baseline (86.448 us; speedup 1.0000x reference)
//
#include <hip/hip_runtime.h>
#include <math.h>

// 16 waves (1024 threads) per batch element. State psi (4096 fp32) split:
//   flat bits [11:6] = lane id (qubits 0..5, qubit i <-> lane bit 5-i)
//   flat bits [5:2]  = wave id (q6=8, q7=4, q8=2, q9=1)  <- LDS cross-wave
//   flat bits [1:0]  = reg  id (q10=bit1, q11=bit0)      <- in-register
//
// R7: 8 waves/SIMD (2 blocks/CU x 16 waves) for 2x latency hiding; q9 is a
// wave bit so each lane computes ONE neuron angle/sincos (its own q9 branch).
// Neuron = RB(+),crY(pi,10,11),RB(-),T,RB(+),crY(-pi,10,11),RB(-) applied in
// factorized form on the in-register (q10,q11) 4-space (half1/half2, R5-
// verified). T = crY(pi, ctrl q11, tgt out) touches only .y components.
// Cross-lane: DPP for xor1/2/8, ds_swizzle for xor4/16/32; cross-wave via
// double-buffered LDS (one barrier per exchange). BitFlip folds into load.

typedef float v2f __attribute__((ext_vector_type(2)));

#define NSLOT 1024  // 16 waves * 64 lanes

__device__ __forceinline__ v2f mk(float a, float b) { v2f r; r.x = a; r.y = b; return r; }

// native sincos: v_sin_f32/v_cos_f32 take revolutions (D = sin(S0*2pi)).
__device__ __forceinline__ void fast_sincos(float a, float* s, float* c) {
    float r = a * 0.15915494309189535f;  // 1/(2*pi)
    *s = __builtin_amdgcn_sinf(r);
    *c = __builtin_amdgcn_cosf(r);
}

template <int XM>
__device__ __forceinline__ float shx(float x) {
    if constexpr (XM == 1) {        // quad_perm [1,0,3,2] = xor 1 (VALU)
        return __int_as_float(__builtin_amdgcn_update_dpp(
            0, __float_as_int(x), 0xB1, 0xF, 0xF, true));
    } else if constexpr (XM == 2) { // quad_perm [2,3,0,1] = xor 2 (VALU)
        return __int_as_float(__builtin_amdgcn_update_dpp(
            0, __float_as_int(x), 0x4E, 0xF, 0xF, true));
    } else if constexpr (XM == 8) { // row_ror:8 -> (i+8)%16 == i^8 (VALU)
        return __int_as_float(__builtin_amdgcn_update_dpp(
            0, __float_as_int(x), 0x128, 0xF, 0xF, true));
    } else {
        return __shfl_xor(x, XM, 64);
    }
}

template <int LM>
__device__ __forceinline__ void lane_ry_t(v2f& V0, v2f& V1, float c, float s, int ln) {
    float ss = (ln & LM) ? s : -s;
    v2f p0 = mk(shx<LM>(V0.x), shx<LM>(V0.y));
    v2f p1 = mk(shx<LM>(V1.x), shx<LM>(V1.y));
    V0 = c * V0 + ss * p0;
    V1 = c * V1 + ss * p1;
}

// cross-wave uncontrolled rY on wave-bit qubit via float4 LDS exchange.
__device__ __forceinline__ void wave_ry(v2f& V0, v2f& V1, int wm, float c, float s,
                                        int wv, int ln, float4* buf) {
    const int slot = wv * 64 + ln;
    buf[slot] = make_float4(V0.x, V0.y, V1.x, V1.y);
    __syncthreads();
    float4 t = buf[(wv ^ wm) * 64 + ln];
    float ss = (wv & wm) ? s : -s;
    V0 = c * V0 + ss * mk(t.x, t.y);
    V1 = c * V1 + ss * mk(t.z, t.w);
}

// First half of the neuron: RB(+), crY(pi,10,11), RB(-)  [R5-verified algebra]
__device__ __forceinline__ void half1(v2f V0, v2f V1, float c, float s,
                                      v2f& u0, v2f& u1) {
    v2f t0 = c * V0 - s * V1;
    v2f t1 = s * V0 + c * V1;
    v2f t1s = __builtin_shufflevector(t1, t1, 1, 0);
    u0 =  c * t0 + mk(-s,  s) * t1s;
    u1 = -s * t0 + mk(-c,  c) * t1s;
}

// Second half: RB(+), crY(-pi,10,11), RB(-)
__device__ __forceinline__ void half2(v2f& V0, v2f& V1, float c, float s,
                                      v2f u0, v2f u1) {
    v2f r0 = c * u0 - s * u1;
    v2f r1 = s * u0 + c * u1;
    v2f r1s = __builtin_shufflevector(r1, r1, 1, 0);
    V0 =  c * r0 + mk( s, -s) * r1s;
    V1 = -s * r0 + mk( c, -c) * r1s;
}

// One quantum neuron. V0=(m0,m1), V1=(m2,m3) on the (q10,q11) subspace.
// buf (float2 view of the dbuf) used only for OUT in {6,7,8,9}.
template <int OUT>
__device__ __forceinline__ void neuron(v2f& V0, v2f& V1, const float* __restrict__ th,
                                       int wv, int ln, float2* buf) {
    // fused angle (HALF angle): bias + lane bits (q0..5) + wave bits (q6..9)
    float a0 = (ln & 32) ? th[0] : 0.f;
    float a1 = (ln & 16) ? th[1] : 0.f;
    float a2 = (ln &  8) ? th[2] : 0.f;
    float a3 = (ln &  4) ? th[3] : 0.f;
    float a4 = (ln &  2) ? th[4] : 0.f;
    float a5 = (ln &  1) ? th[5] : 0.f;
    float wsum = th[10];
    if (wv & 8) wsum += th[6];
    if (wv & 4) wsum += th[7];
    if (wv & 2) wsum += th[8];
    if (wv & 1) wsum += th[9];
    float phih = 0.5f * (((a0 + a1) + (a2 + a3)) + ((a4 + a5) + wsum));

    float s, c;
    fast_sincos(phih, &s, &c);

    v2f u0, u1;
    half1(V0, V1, c, s, u0, u1);

    // T = crY(pi, ctrl q11, tgt OUT) on the q11=1 (.y) components
    if constexpr (OUT < 6) {
        constexpr int LM = 1 << (5 - OUT);
        float ss = (ln & LM) ? 1.f : -1.f;
        u0.y = ss * shx<LM>(u0.y);
        u1.y = ss * shx<LM>(u1.y);
    } else {
        constexpr int WM = 1 << (9 - OUT);
        const int slot = wv * 64 + ln;
        buf[slot] = make_float2(u0.y, u1.y);
        __syncthreads();
        float2 t = buf[(wv ^ WM) * 64 + ln];
        float ss = (wv & WM) ? 1.f : -1.f;
        u0.y = ss * t.x;
        u1.y = ss * t.y;
    }

    half2(V0, V1, c, s, u0, u1);
}

__global__ __launch_bounds__(1024, 8) void rvqe_kernel(
    const float* __restrict__ psi_in,   // (B, 4096)
    const int*   __restrict__ inp,      // (6,)
    const float* __restrict__ ut,       // (2, 10)
    const float* __restrict__ nt,       // (2, 10, 11)
    float* __restrict__ out_probs,      // (B, 64)
    float* __restrict__ out_psi)        // (B, 4096)
{
    __shared__ float4 xbuf[2][NSLOT];  // 2 x 16 KB

    const int b   = blockIdx.x;
    const int tid = threadIdx.x;
    const int ln  = tid & 63;
    const int wv  = tid >> 6;   // bit3=q6, bit2=q7, bit1=q8, bit0=q9
    int bi = 0;

    // BitFlip: fold X on input lanes into load address
    int flip = 0;
#pragma unroll
    for (int l = 0; l < 6; ++l)
        if (inp[l] == 1) flip |= 1 << (5 - l);

    v2f V0, V1;
    {
        const float* src = psi_in + (size_t)b * 4096 + (((ln ^ flip) & 63) << 6) + (wv << 2);
        float4 t = *(const float4*)src;
        V0 = mk(t.x, t.y); V1 = mk(t.z, t.w);
    }

    for (int s = 0; s < 2; ++s) {
        const float* uts = ut + s * 10;
        const float* nts = nt + (size_t)s * 110;

        // ---- UnitaryLayer: rY(uts[i]) on qubit i ----
        {
            float cc, ss;
            fast_sincos(0.5f * uts[0], &ss, &cc); lane_ry_t<32>(V0, V1, cc, ss, ln);
            fast_sincos(0.5f * uts[1], &ss, &cc); lane_ry_t<16>(V0, V1, cc, ss, ln);
            fast_sincos(0.5f * uts[2], &ss, &cc); lane_ry_t<8>(V0, V1, cc, ss, ln);
            fast_sincos(0.5f * uts[3], &ss, &cc); lane_ry_t<4>(V0, V1, cc, ss, ln);
            fast_sincos(0.5f * uts[4], &ss, &cc); lane_ry_t<2>(V0, V1, cc, ss, ln);
            fast_sincos(0.5f * uts[5], &ss, &cc); lane_ry_t<1>(V0, V1, cc, ss, ln);
            fast_sincos(0.5f * uts[6], &ss, &cc);
            wave_ry(V0, V1, 8, cc, ss, wv, ln, xbuf[bi]); bi ^= 1;
            fast_sincos(0.5f * uts[7], &ss, &cc);
            wave_ry(V0, V1, 4, cc, ss, wv, ln, xbuf[bi]); bi ^= 1;
            fast_sincos(0.5f * uts[8], &ss, &cc);
            wave_ry(V0, V1, 2, cc, ss, wv, ln, xbuf[bi]); bi ^= 1;
            fast_sincos(0.5f * uts[9], &ss, &cc);
            wave_ry(V0, V1, 1, cc, ss, wv, ln, xbuf[bi]); bi ^= 1;
        }

        // ---- QuantumNeuronLayer, fully unrolled (compile-time masks) ----
        neuron<0>(V0, V1, nts + 0 * 11, wv, ln, nullptr);
        neuron<1>(V0, V1, nts + 1 * 11, wv, ln, nullptr);
        neuron<2>(V0, V1, nts + 2 * 11, wv, ln, nullptr);
        neuron<3>(V0, V1, nts + 3 * 11, wv, ln, nullptr);
        neuron<4>(V0, V1, nts + 4 * 11, wv, ln, nullptr);
        neuron<5>(V0, V1, nts + 5 * 11, wv, ln, nullptr);
        neuron<6>(V0, V1, nts + 6 * 11, wv, ln, (float2*)xbuf[bi]); bi ^= 1;
        neuron<7>(V0, V1, nts + 7 * 11, wv, ln, (float2*)xbuf[bi]); bi ^= 1;
        neuron<8>(V0, V1, nts + 8 * 11, wv, ln, (float2*)xbuf[bi]); bi ^= 1;
        neuron<9>(V0, V1, nts + 9 * 11, wv, ln, (float2*)xbuf[bi]); bi ^= 1;
    }

    // ---- probs: marginal |amp|^2 over qubits 6..11 (wave + reg bits) ----
    float acc = V0.x * V0.x + V0.y * V0.y + V1.x * V1.x + V1.y * V1.y;
    {
        float* pb = (float*)&xbuf[bi][0];  // dbuf invariant: safe to write pre-barrier
        pb[wv * 64 + ln] = acc;
        __syncthreads();
        if (wv == 0) {
            float t = 0.f;
#pragma unroll
            for (int w = 0; w < 16; ++w) t += pb[w * 64 + ln];
            out_probs[(size_t)b * 64 + ln] = t;
        }
    }

    // ---- write final psi ----
    float* dst = out_psi + (size_t)b * 4096 + (ln << 6) + (wv << 2);
    *(float4*)dst = make_float4(V0.x, V0.y, V1.x, V1.y);
}

extern "C" void kernel_launch(void* const* d_in, const int* in_sizes, int n_in,
                              void* d_out, int out_size, void* d_ws, size_t ws_size,
                              hipStream_t stream) {
    const float* psi = (const float*)d_in[0];
    const int*   inp = (const int*)d_in[1];
    const float* ut  = (const float*)d_in[2];
    const float* nt  = (const float*)d_in[3];

    const int B = in_sizes[0] >> 12;          // 4096 amplitudes per state
    float* probs = (float*)d_out;             // (B, 64) first
    float* opsi  = probs + (size_t)B * 64;    // then (B, 4096)

    rvqe_kernel<<<B, 1024, 0, stream>>>(psi, inp, ut, nt, probs, opsi);
}

// Round 8
// 85.053 us; speedup vs baseline: 1.0164x; 1.0164x over previous
//
#include <hip/hip_runtime.h>
#include <math.h>

// FINAL (revert to R6, the best measured variant: 83.9 us total).
// 8 waves (512 threads) per batch element. State psi (4096 fp32) split:
//   flat bits [11:6] = lane id (qubits 0..5, qubit i <-> lane bit 5-i)
//   flat bits [5:3]  = wave id (q6=4, q7=2, q8=1)   <- LDS cross-wave (b128)
//   flat bits [2:0]  = reg  id (q9=bit2, q10=bit1, q11=bit0) <- in-register
//
// Neuron = RB(+),crY(pi,10,11),RB(-),T,RB(+),crY(-pi,10,11),RB(-), applied in
// factorized form (half1/half2; symbolically verified vs dense M1/M2).
// All sincos via native v_sin_f32/v_cos_f32 (args in revolutions).
// Cross-lane: DPP quad_perm (xor1/2), row_ror:8 (xor8); ds_swizzle otherwise;
// cross-wave via double-buffered LDS (one barrier per exchange).
// BitFlip folds into the initial load address.
//
// Session note: R4 (DS cuts), R5 (-35% VALU), R6 (native sincos), R7 (16
// waves) all land 84-86.5 total; bench floor is ~56 us harness fill traffic
// (268 MB ws-poison at ~80% HBM peak) + ~27 us kernel plateau.

typedef float v2f __attribute__((ext_vector_type(2)));

#define NSLOT 512  // 8 waves * 64 lanes

__device__ __forceinline__ v2f mk(float a, float b) { v2f r; r.x = a; r.y = b; return r; }

// native sincos: v_sin_f32/v_cos_f32 take revolutions (D = sin(S0*2pi)).
__device__ __forceinline__ void fast_sincos(float a, float* s, float* c) {
    float r = a * 0.15915494309189535f;  // 1/(2*pi)
    *s = __builtin_amdgcn_sinf(r);
    *c = __builtin_amdgcn_cosf(r);
}

template <int XM>
__device__ __forceinline__ float shx(float x) {
    if constexpr (XM == 1) {        // quad_perm [1,0,3,2] = xor 1 (VALU)
        return __int_as_float(__builtin_amdgcn_update_dpp(
            0, __float_as_int(x), 0xB1, 0xF, 0xF, true));
    } else if constexpr (XM == 2) { // quad_perm [2,3,0,1] = xor 2 (VALU)
        return __int_as_float(__builtin_amdgcn_update_dpp(
            0, __float_as_int(x), 0x4E, 0xF, 0xF, true));
    } else if constexpr (XM == 8) { // row_ror:8 -> (i+8)%16 == i^8 (VALU)
        return __int_as_float(__builtin_amdgcn_update_dpp(
            0, __float_as_int(x), 0x128, 0xF, 0xF, true));
    } else {
        return __shfl_xor(x, XM, 64);
    }
}

template <int LM>
__device__ __forceinline__ void lane_ry_t(v2f (&V)[4], float c, float s, int ln) {
    float ss = (ln & LM) ? s : -s;
#pragma unroll
    for (int k = 0; k < 4; ++k) {
        v2f p = mk(shx<LM>(V[k].x), shx<LM>(V[k].y));
        V[k] = c * V[k] + ss * p;
    }
}

// cross-wave uncontrolled rY on wave-bit qubit via b128 LDS exchange.
__device__ __forceinline__ void wave_ry(v2f (&V)[4], int wm, float c, float s,
                                        int wv, int ln, float4* buf) {
    const int slot = wv * 64 + ln;
    buf[slot]         = make_float4(V[0].x, V[0].y, V[1].x, V[1].y);
    buf[NSLOT + slot] = make_float4(V[2].x, V[2].y, V[3].x, V[3].y);
    __syncthreads();
    const int pslot = (wv ^ wm) * 64 + ln;
    float ss = (wv & wm) ? s : -s;
    float4 t0 = buf[pslot];
    float4 t1 = buf[NSLOT + pslot];
    V[0] = c * V[0] + ss * mk(t0.x, t0.y);
    V[1] = c * V[1] + ss * mk(t0.z, t0.w);
    V[2] = c * V[2] + ss * mk(t1.x, t1.y);
    V[3] = c * V[3] + ss * mk(t1.z, t1.w);
}

// First half of the neuron on one q9-group: RB(+), crY(pi,10,11), RB(-).
__device__ __forceinline__ void half1(v2f V0, v2f V1, float c, float s,
                                      v2f& u0, v2f& u1) {
    v2f t0 = c * V0 - s * V1;
    v2f t1 = s * V0 + c * V1;
    v2f t1s = __builtin_shufflevector(t1, t1, 1, 0);
    u0 =  c * t0 + mk(-s,  s) * t1s;
    u1 = -s * t0 + mk(-c,  c) * t1s;
}

// Second half: RB(+), crY(-pi,10,11), RB(-).
__device__ __forceinline__ void half2(v2f& V0, v2f& V1, float c, float s,
                                      v2f u0, v2f u1) {
    v2f r0 = c * u0 - s * u1;
    v2f r1 = s * u0 + c * u1;
    v2f r1s = __builtin_shufflevector(r1, r1, 1, 0);
    V0 =  c * r0 + mk( s, -s) * r1s;
    V1 = -s * r0 + mk( c, -c) * r1s;
}

// One quantum neuron, OUT = target qubit. V[0],V[1] = q9=0 group; V[2],V[3] =
// q9=1 group. buf only used for OUT in {6,7,8}.
template <int OUT>
__device__ __forceinline__ void neuron(v2f (&V)[4], const float* __restrict__ th,
                                       int wv, int ln, float4* buf) {
    // fused angle (HALF angle for the RB rotations)
    float a0 = (ln & 32) ? th[0] : 0.f;
    float a1 = (ln & 16) ? th[1] : 0.f;
    float a2 = (ln &  8) ? th[2] : 0.f;
    float a3 = (ln &  4) ? th[3] : 0.f;
    float a4 = (ln &  2) ? th[4] : 0.f;
    float a5 = (ln &  1) ? th[5] : 0.f;
    float wsum = th[10];
    if (wv & 4) wsum += th[6];
    if (wv & 2) wsum += th[7];
    if (wv & 1) wsum += th[8];
    float phih = 0.5f * (((a0 + a1) + (a2 + a3)) + ((a4 + a5) + wsum));

    float sA, cA, sB, cB;
    fast_sincos(phih, &sA, &cA);
    fast_sincos(phih + 0.5f * th[9], &sB, &cB);

    v2f uA0, uA1, uB0, uB1;
    half1(V[0], V[1], cA, sA, uA0, uA1);
    half1(V[2], V[3], cB, sB, uB0, uB1);

    // T = crY(pi, ctrl q11, tgt OUT) on the q11=1 (.y) components
    if constexpr (OUT < 6) {
        constexpr int LM = 1 << (5 - OUT);
        float ss = (ln & LM) ? 1.f : -1.f;
        uA0.y = ss * shx<LM>(uA0.y);
        uA1.y = ss * shx<LM>(uA1.y);
        uB0.y = ss * shx<LM>(uB0.y);
        uB1.y = ss * shx<LM>(uB1.y);
    } else if constexpr (OUT < 9) {
        constexpr int WM = 1 << (8 - OUT);
        const int slot = wv * 64 + ln;
        buf[slot] = make_float4(uA0.y, uA1.y, uB0.y, uB1.y);
        __syncthreads();
        const int pslot = (wv ^ WM) * 64 + ln;
        float ss = (wv & WM) ? 1.f : -1.f;
        float4 t = buf[pslot];
        uA0.y = ss * t.x; uA1.y = ss * t.y; uB0.y = ss * t.z; uB1.y = ss * t.w;
    } else {  // OUT == 9: q9 = reg-group bit; new(A) = -old(B), new(B) = old(A)
        float t1 = uA0.y, t3 = uA1.y;
        uA0.y = -uB0.y; uA1.y = -uB1.y;
        uB0.y = t1;     uB1.y = t3;
    }

    half2(V[0], V[1], cA, sA, uA0, uA1);
    half2(V[2], V[3], cB, sB, uB0, uB1);
}

__global__ __launch_bounds__(512, 4) void rvqe_kernel(
    const float* __restrict__ psi_in,   // (B, 4096)
    const int*   __restrict__ inp,      // (6,)
    const float* __restrict__ ut,       // (2, 10)
    const float* __restrict__ nt,       // (2, 10, 11)
    float* __restrict__ out_probs,      // (B, 64)
    float* __restrict__ out_psi)        // (B, 4096)
{
    __shared__ float4 xbuf[2][2 * NSLOT];  // 2 x 16 KB

    const int b   = blockIdx.x;
    const int tid = threadIdx.x;
    const int ln  = tid & 63;
    const int wv  = tid >> 6;   // bit2=q6, bit1=q7, bit0=q8
    int bi = 0;

    // BitFlip: fold X on input lanes into load address
    int flip = 0;
#pragma unroll
    for (int l = 0; l < 6; ++l)
        if (inp[l] == 1) flip |= 1 << (5 - l);

    v2f V[4];
    {
        const float* src = psi_in + (size_t)b * 4096 + (((ln ^ flip) & 63) << 6) + (wv << 3);
        float4 t0 = ((const float4*)src)[0];
        float4 t1 = ((const float4*)src)[1];
        V[0] = mk(t0.x, t0.y); V[1] = mk(t0.z, t0.w);
        V[2] = mk(t1.x, t1.y); V[3] = mk(t1.z, t1.w);
    }

    for (int s = 0; s < 2; ++s) {
        const float* uts = ut + s * 10;
        const float* nts = nt + (size_t)s * 110;

        // ---- UnitaryLayer: rY(uts[i]) on qubit i ----
        {
            float cc, ss;
            fast_sincos(0.5f * uts[0], &ss, &cc); lane_ry_t<32>(V, cc, ss, ln);
            fast_sincos(0.5f * uts[1], &ss, &cc); lane_ry_t<16>(V, cc, ss, ln);
            fast_sincos(0.5f * uts[2], &ss, &cc); lane_ry_t<8>(V, cc, ss, ln);
            fast_sincos(0.5f * uts[3], &ss, &cc); lane_ry_t<4>(V, cc, ss, ln);
            fast_sincos(0.5f * uts[4], &ss, &cc); lane_ry_t<2>(V, cc, ss, ln);
            fast_sincos(0.5f * uts[5], &ss, &cc); lane_ry_t<1>(V, cc, ss, ln);
            fast_sincos(0.5f * uts[6], &ss, &cc);
            wave_ry(V, 4, cc, ss, wv, ln, xbuf[bi]); bi ^= 1;
            fast_sincos(0.5f * uts[7], &ss, &cc);
            wave_ry(V, 2, cc, ss, wv, ln, xbuf[bi]); bi ^= 1;
            fast_sincos(0.5f * uts[8], &ss, &cc);
            wave_ry(V, 1, cc, ss, wv, ln, xbuf[bi]); bi ^= 1;
            fast_sincos(0.5f * uts[9], &ss, &cc);
            // q9 = reg-group bit: A<->B
            v2f n0 = cc * V[0] - ss * V[2];
            v2f n2 = ss * V[0] + cc * V[2];
            v2f n1 = cc * V[1] - ss * V[3];
            v2f n3 = ss * V[1] + cc * V[3];
            V[0] = n0; V[1] = n1; V[2] = n2; V[3] = n3;
        }

        // ---- QuantumNeuronLayer, fully unrolled (compile-time masks) ----
        neuron<0>(V, nts + 0 * 11, wv, ln, nullptr);
        neuron<1>(V, nts + 1 * 11, wv, ln, nullptr);
        neuron<2>(V, nts + 2 * 11, wv, ln, nullptr);
        neuron<3>(V, nts + 3 * 11, wv, ln, nullptr);
        neuron<4>(V, nts + 4 * 11, wv, ln, nullptr);
        neuron<5>(V, nts + 5 * 11, wv, ln, nullptr);
        neuron<6>(V, nts + 6 * 11, wv, ln, xbuf[bi]); bi ^= 1;
        neuron<7>(V, nts + 7 * 11, wv, ln, xbuf[bi]); bi ^= 1;
        neuron<8>(V, nts + 8 * 11, wv, ln, xbuf[bi]); bi ^= 1;
        neuron<9>(V, nts + 9 * 11, wv, ln, nullptr);
    }

    // ---- probs: marginal |amp|^2 over qubits 6..11 (wave + reg bits) ----
    float acc = 0.f;
#pragma unroll
    for (int k = 0; k < 4; ++k) acc += V[k].x * V[k].x + V[k].y * V[k].y;
    {
        float* pb = (float*)&xbuf[bi][0];  // dbuf invariant: safe to write pre-barrier
        pb[wv * 64 + ln] = acc;
        __syncthreads();
        if (wv == 0) {
            float t = 0.f;
#pragma unroll
            for (int w = 0; w < 8; ++w) t += pb[w * 64 + ln];
            out_probs[(size_t)b * 64 + ln] = t;
        }
    }

    // ---- write final psi ----
    float* dst = out_psi + (size_t)b * 4096 + (ln << 6) + (wv << 3);
    ((float4*)dst)[0] = make_float4(V[0].x, V[0].y, V[1].x, V[1].y);
    ((float4*)dst)[1] = make_float4(V[2].x, V[2].y, V[3].x, V[3].y);
}

extern "C" void kernel_launch(void* const* d_in, const int* in_sizes, int n_in,
                              void* d_out, int out_size, void* d_ws, size_t ws_size,
                              hipStream_t stream) {
    const float* psi = (const float*)d_in[0];
    const int*   inp = (const int*)d_in[1];
    const float* ut  = (const float*)d_in[2];
    const float* nt  = (const float*)d_in[3];

    const int B = in_sizes[0] >> 12;          // 4096 amplitudes per state
    float* probs = (float*)d_out;             // (B, 64) first
    float* opsi  = probs + (size_t)B * 64;    // then (B, 4096)

    rvqe_kernel<<<B, 512, 0, stream>>>(psi, inp, ut, nt, probs, opsi);
}